// Round 3
// baseline (904.447 us; speedup 1.0000x reference)
//
#include <hip/hip_runtime.h>

typedef _Float16 half8 __attribute__((ext_vector_type(8)));
typedef _Float16 half4 __attribute__((ext_vector_type(4)));
typedef float floatx4 __attribute__((ext_vector_type(4)));
typedef float floatx16 __attribute__((ext_vector_type(16)));

// LDS column-group swizzle (8-elem granularity) so fragment reads spread banks.
#define SWZ(r) ((((r) & 7) << 1) | (((r) >> 3) & 1))

__device__ __forceinline__ void gld16(const void* g, void* l) {
  __builtin_amdgcn_global_load_lds(
      (const __attribute__((address_space(1))) unsigned int*)g,
      (__attribute__((address_space(3))) unsigned int*)l, 16, 0, 0);
}

// ---------------- fused fp32 -> f16 converts + bias concat (1 dispatch) ----------------
__global__ void convert_all(const float* __restrict__ x, const float* __restrict__ Wq,
                            const float* __restrict__ Wk, const float* __restrict__ Wv,
                            const float* __restrict__ Wo, const float* __restrict__ bq,
                            const float* __restrict__ bk, const float* __restrict__ bv,
                            _Float16* __restrict__ xb, _Float16* __restrict__ wqkv,
                            _Float16* __restrict__ wo_b, float* __restrict__ biasc) {
  long i = (long)blockIdx.x * 256 + threadIdx.x;
  const long N0 = 2097152, N1 = N0 + 2097152, N2 = N1 + 524288, N3 = N2 + 524288,
             N4 = N3 + 2097152;
  const float* s;
  _Float16* d;
  long j;
  if (i < N0) { s = x; d = xb; j = i; }
  else if (i < N1) { s = Wq; d = wqkv; j = i - N0; }
  else if (i < N2) { s = Wk; d = wqkv + (size_t)4096 * 4096; j = i - N1; }
  else if (i < N3) { s = Wv; d = wqkv + (size_t)5120 * 4096; j = i - N2; }
  else if (i < N4) { s = Wo; d = wo_b; j = i - N3; }
  else {
    long k = i - N4;
    if (k < 4096) biasc[k] = bq[k];
    else if (k < 5120) biasc[k] = bk[k - 4096];
    else if (k < 6144) biasc[k] = bv[k - 5120];
    return;
  }
  float4 a = ((const float4*)s)[2 * j];
  float4 b2 = ((const float4*)s)[2 * j + 1];
  half8 h;
  h[0] = (_Float16)a.x; h[1] = (_Float16)a.y; h[2] = (_Float16)a.z; h[3] = (_Float16)a.w;
  h[4] = (_Float16)b2.x; h[5] = (_Float16)b2.y; h[6] = (_Float16)b2.z; h[7] = (_Float16)b2.w;
  ((half8*)d)[j] = h;
}

// ---------------- GEMM (proven 128x128): C[m,n] = sum_k A[m,k]*B[n,k] (+bias[n]) ----------------
template <typename OutT, bool HasBias>
__global__ __launch_bounds__(256) void gemm_bt(const _Float16* __restrict__ A,
                                               const _Float16* __restrict__ B,
                                               const float* __restrict__ bias,
                                               OutT* __restrict__ C, int M, int N, int K) {
  __shared__ _Float16 as[128 * 64];
  __shared__ _Float16 bs[128 * 64];
  const int tid = threadIdx.x;
  const int w = tid >> 6, lane = tid & 63;
  const int quad = lane >> 4, l16 = lane & 15;
  const int M0 = blockIdx.y * 128, N0 = blockIdx.x * 128;
  const int wm = (w >> 1) * 64, wn = (w & 1) * 64;

  floatx4 acc[4][4];
#pragma unroll
  for (int i = 0; i < 4; ++i)
#pragma unroll
    for (int j = 0; j < 4; ++j) acc[i][j] = (floatx4){0.f, 0.f, 0.f, 0.f};

  const int sr = tid >> 3, g0 = tid & 7;
  const int csw = (g0 ^ (sr & 7)) * 8;
  const _Float16* Ag[4];
  const _Float16* Bg[4];
  _Float16* asd[4];
  _Float16* bsd[4];
#pragma unroll
  for (int c = 0; c < 4; ++c) {
    Ag[c] = A + (size_t)(M0 + c * 32 + sr) * K + csw;
    Bg[c] = B + (size_t)(N0 + c * 32 + sr) * K + csw;
    asd[c] = &as[(c * 32 + w * 8) * 64];
    bsd[c] = &bs[(c * 32 + w * 8) * 64];
  }

  int aoff[4][2], boff[4][2];
#pragma unroll
  for (int mi = 0; mi < 4; ++mi)
#pragma unroll
    for (int kd = 0; kd < 2; ++kd) {
      int ra = wm + mi * 16 + l16;
      aoff[mi][kd] = ra * 64 + (((kd * 4 + quad) ^ (ra & 7)) * 8);
      int rb = wn + mi * 16 + l16;
      boff[mi][kd] = rb * 64 + (((kd * 4 + quad) ^ (rb & 7)) * 8);
    }

  for (int kk = 0; kk < K; kk += 64) {
    __syncthreads();
#pragma unroll
    for (int c = 0; c < 4; ++c) gld16(Ag[c] + kk, asd[c]);
#pragma unroll
    for (int c = 0; c < 4; ++c) gld16(Bg[c] + kk, bsd[c]);
    __syncthreads();
#pragma unroll
    for (int kd = 0; kd < 2; ++kd) {
      half8 af[4], bf[4];
#pragma unroll
      for (int i = 0; i < 4; ++i) af[i] = *(const half8*)&as[aoff[i][kd]];
#pragma unroll
      for (int i = 0; i < 4; ++i) bf[i] = *(const half8*)&bs[boff[i][kd]];
#pragma unroll
      for (int mi = 0; mi < 4; ++mi)
#pragma unroll
        for (int ni = 0; ni < 4; ++ni)
          acc[mi][ni] = __builtin_amdgcn_mfma_f32_16x16x32_f16(af[mi], bf[ni], acc[mi][ni], 0, 0, 0);
    }
  }

#pragma unroll
  for (int mi = 0; mi < 4; ++mi)
#pragma unroll
    for (int ni = 0; ni < 4; ++ni) {
      int row = M0 + wm + mi * 16 + quad * 4;
      int col = N0 + wn + ni * 16 + l16;
      float bvv = HasBias ? bias[col] : 0.f;
#pragma unroll
      for (int r = 0; r < 4; ++r) {
        float v = acc[mi][ni][r] + bvv;
        C[(size_t)(row + r) * N + col] = (OutT)v;
      }
    }
}

// ---------------- GEMM 256x256 8-phase (out-proj: 256 blocks = 1/CU exactly) --------
template <typename OutT, bool HasBias>
__global__ __launch_bounds__(512, 2) void gemm256(const _Float16* __restrict__ A,
                                                  const _Float16* __restrict__ B,
                                                  const float* __restrict__ bias,
                                                  OutT* __restrict__ C, int M, int N, int K) {
  __shared__ _Float16 as[2][256 * 64];
  __shared__ _Float16 bs[2][256 * 64];
  const int tid = threadIdx.x;
  const int w = tid >> 6, lane = tid & 63;
  const int quad = lane >> 4, l16 = lane & 15;
  const int sw7 = l16 & 7;
  const int M0 = blockIdx.y * 256, N0 = blockIdx.x * 256;
  const int wm = (w >> 2) * 128, wn = (w & 3) * 64;
  const int NT = K >> 6;

  floatx4 acc[8][4];
#pragma unroll
  for (int i = 0; i < 8; ++i)
#pragma unroll
    for (int j = 0; j < 4; ++j) acc[i][j] = (floatx4){0.f, 0.f, 0.f, 0.f};

  const int sr = tid >> 3;
  const int csw = ((tid & 7) ^ (sr & 7)) * 8;
  const _Float16* Ag[4];
  const _Float16* Bg[4];
#pragma unroll
  for (int j = 0; j < 4; ++j) {
    Ag[j] = A + (size_t)(M0 + j * 64 + sr) * K + csw;
    Bg[j] = B + (size_t)(N0 + j * 64 + sr) * K + csw;
  }

#define STA(p, t, j) gld16(Ag[j] + (size_t)(t) * 64, &as[p][(j) * 4096 + w * 512])
#define STB(p, t, j) gld16(Bg[j] + (size_t)(t) * 64, &bs[p][(j) * 4096 + w * 512])

#define FRA(p, q, mi, kd) \
  (*(const half8*)&as[p][(wm + (q) * 32 + (mi) * 16 + l16) * 64 + ((((kd) * 4 + quad) ^ sw7) * 8)])
#define FRB(p, ni, kd) \
  (*(const half8*)&bs[p][(wn + (ni) * 16 + l16) * 64 + ((((kd) * 4 + quad) ^ sw7) * 8)])

#define LD_A(p, q)                                   \
  _Pragma("unroll") for (int kd = 0; kd < 2; ++kd)   \
  _Pragma("unroll") for (int mi = 0; mi < 2; ++mi)   \
      af[mi][kd] = FRA(p, q, mi, kd);

#define LD_B(p)                                      \
  _Pragma("unroll") for (int kd = 0; kd < 2; ++kd)   \
  _Pragma("unroll") for (int ni = 0; ni < 4; ++ni)   \
      bf[ni][kd] = FRB(p, ni, kd);

#define PH_COMPUTE(q)                                                                  \
  __builtin_amdgcn_s_barrier();                                                        \
  asm volatile("s_waitcnt lgkmcnt(0)" ::: "memory");                                   \
  __builtin_amdgcn_sched_barrier(0);                                                   \
  __builtin_amdgcn_s_setprio(1);                                                       \
  _Pragma("unroll") for (int kd = 0; kd < 2; ++kd)                                     \
  _Pragma("unroll") for (int mi = 0; mi < 2; ++mi)                                     \
  _Pragma("unroll") for (int ni = 0; ni < 4; ++ni)                                     \
      acc[(q) * 2 + mi][ni] = __builtin_amdgcn_mfma_f32_16x16x32_f16(                  \
          af[mi][kd], bf[ni][kd], acc[(q) * 2 + mi][ni], 0, 0, 0);                     \
  __builtin_amdgcn_s_setprio(0);

  half8 bf[4][2], af[2][2];

  STA(0, 0, 0); STA(0, 0, 1); STA(0, 0, 2); STA(0, 0, 3);
  STB(0, 0, 0); STB(0, 0, 1); STB(0, 0, 2); STB(0, 0, 3);
  STB(1, 1, 0); STB(1, 1, 1); STB(1, 1, 2); STB(1, 1, 3);
  asm volatile("s_waitcnt vmcnt(4)" ::: "memory");
  __builtin_amdgcn_s_barrier();

  for (int t = 0; t < NT; t += 2) {
    const int t2 = (t + 2 < NT) ? t + 2 : t;
    const int t3 = (t + 3 < NT) ? t + 3 : t + 1;

    LD_B(0); LD_A(0, 0);
    STA(1, t + 1, 0); STA(1, t + 1, 1); STA(1, t + 1, 2); STA(1, t + 1, 3);
    PH_COMPUTE(0);
    __builtin_amdgcn_s_barrier();

    LD_A(0, 1);
    STB(0, t2, 0); STB(0, t2, 1);
    PH_COMPUTE(1);
    __builtin_amdgcn_s_barrier();

    LD_A(0, 2);
    STB(0, t2, 2); STB(0, t2, 3);
    PH_COMPUTE(2);
    __builtin_amdgcn_s_barrier();

    LD_A(0, 3);
    PH_COMPUTE(3);
    asm volatile("s_waitcnt vmcnt(4)" ::: "memory");
    __builtin_amdgcn_sched_barrier(0);
    __builtin_amdgcn_s_barrier();

    LD_B(1); LD_A(1, 0);
    STA(0, t2, 0); STA(0, t2, 1);
    PH_COMPUTE(0);
    __builtin_amdgcn_s_barrier();

    LD_A(1, 1);
    STA(0, t2, 2); STA(0, t2, 3);
    PH_COMPUTE(1);
    __builtin_amdgcn_s_barrier();

    LD_A(1, 2);
    STB(1, t3, 0); STB(1, t3, 1);
    PH_COMPUTE(2);
    __builtin_amdgcn_s_barrier();

    LD_A(1, 3);
    STB(1, t3, 2); STB(1, t3, 3);
    PH_COMPUTE(3);
    asm volatile("s_waitcnt vmcnt(4)" ::: "memory");
    __builtin_amdgcn_sched_barrier(0);
    __builtin_amdgcn_s_barrier();
  }
  asm volatile("s_waitcnt vmcnt(0)" ::: "memory");

#pragma unroll
  for (int mf = 0; mf < 8; ++mf)
#pragma unroll
    for (int ni = 0; ni < 4; ++ni) {
      int row = M0 + wm + mf * 16 + quad * 4;
      int col = N0 + wn + ni * 16 + l16;
      float bvv = HasBias ? bias[col] : 0.f;
#pragma unroll
      for (int r = 0; r < 4; ++r) C[(size_t)(row + r) * N + col] = (OutT)(acc[mf][ni][r] + bvv);
    }
#undef STA
#undef STB
#undef FRA
#undef FRB
#undef LD_A
#undef LD_B
#undef PH_COMPUTE
}

// ---------------- RoPE for Q (scaled by log2e/sqrt(HD)) and K ----------------
__global__ void rope_qk(const _Float16* __restrict__ qkv, const float* __restrict__ cosb,
                        const float* __restrict__ sinb, _Float16* __restrict__ q_r,
                        _Float16* __restrict__ k_r) {
  int t = blockIdx.x * 256 + threadIdx.x;
  int d = t & 63;
  int r = t >> 6;
  int hh = r % 40;
  int r2 = r / 40;
  int s = r2 & 2047;
  int b = r2 >> 11;
  size_t mrow = (size_t)(b * 2048 + s) * 6144;
  float c = cosb[s * 128 + d], sn = sinb[s * 128 + d];
  if (hh < 32) {
    size_t base = mrow + hh * 128 + d;
    float x1 = (float)qkv[base], x2 = (float)qkv[base + 64];
    const float sc = 0.12751744737079736f;  // log2(e)/sqrt(128)
    float o1 = (x1 * c - x2 * sn) * sc;
    float o2 = (x2 * c + x1 * sn) * sc;
    size_t ob = ((size_t)((b * 32 + hh) * 2048 + s)) * 128 + d;
    q_r[ob] = (_Float16)o1;
    q_r[ob + 64] = (_Float16)o2;
  } else {
    int hk = hh - 32;
    size_t base = mrow + 4096 + hk * 128 + d;
    float x1 = (float)qkv[base], x2 = (float)qkv[base + 64];
    float o1 = x1 * c - x2 * sn;
    float o2 = x2 * c + x1 * sn;
    size_t ob = ((size_t)((b * 8 + hk) * 2048 + s)) * 128 + d;
    k_r[ob] = (_Float16)o1;
    k_r[ob + 64] = (_Float16)o2;
  }
}

// ---------------- V transpose: qkv v-part -> v_t[b][hv][d][s] ----------------
__global__ void v_transpose(const _Float16* __restrict__ qkv, _Float16* __restrict__ v_t) {
  __shared__ _Float16 tile[32][33];
  int st = blockIdx.x * 32, dt = blockIdx.y * 32, bh = blockIdx.z;
  int tx = threadIdx.x & 31, ty = threadIdx.x >> 5;
  int b = bh >> 3, hv = bh & 7;
#pragma unroll
  for (int j = 0; j < 4; ++j) {
    int s = st + ty + j * 8;
    tile[ty + j * 8][tx] = qkv[(size_t)(b * 2048 + s) * 6144 + 5120 + hv * 128 + dt + tx];
  }
  __syncthreads();
#pragma unroll
  for (int j = 0; j < 4; ++j)
    v_t[((size_t)bh * 128 + dt + ty + j * 8) * 2048 + st + tx] = tile[tx][ty + j * 8];
}

// ---------------- Flash attention: S^T form, 32x32x16 MFMA ----------------
// Q-tile 256 (8 waves, 512 thr), KVBLK=64, K/V double-buffered, dedicated P^T region.
// LDS = 2x16K (K) + 2x16K (V) + 32K (P) = 96KB -> 1 block/CU, 8 waves (2/SIMD).
// vs prior: half the steps per (b,h), half the K/V staging bytes, 2 barriers/step
// (P in its own region is wave-private -> no 3rd barrier), setprio around MFMA.
__global__ __launch_bounds__(512, 2) void attn_kernel(const _Float16* __restrict__ q_r,
                                                      const _Float16* __restrict__ k_r,
                                                      const _Float16* __restrict__ v_t,
                                                      _Float16* __restrict__ att) {
  __shared__ __align__(16) _Float16 kbuf[2][64 * 128];  // K [kv64][d128]
  __shared__ __align__(16) _Float16 vbuf[2][128 * 64];  // V^T [d128][kv64]
  __shared__ __align__(16) _Float16 pbuf[256 * 64];     // P^T [q256][kv64]
  const int tid = threadIdx.x;
  const int w = tid >> 6, lane = tid & 63;
  const int l32 = lane & 31, hi = lane >> 5;
  const int qb = 7 - blockIdx.x;  // heavy q-tiles dispatch first
  const int h = blockIdx.y, b = blockIdx.z;
  const int q0 = qb * 256;
  const _Float16* qh = q_r + ((size_t)(b * 32 + h) * 2048) * 128;
  const _Float16* kh = k_r + ((size_t)(b * 8 + (h >> 2)) * 2048) * 128;
  const _Float16* vh = v_t + ((size_t)(b * 8 + (h >> 2)) * 128) * 2048;

  const int ql = w * 32 + l32;  // 0..255
  const int myq = q0 + ql;
  const int swq7 = ql & 7;   // 8-group swizzle key for 64-wide P rows
  const int swl = SWZ(l32);  // 16-group swizzle key for 128-wide K rows

  half8 bq[8];
#pragma unroll
  for (int kd = 0; kd < 8; ++kd)
    bq[kd] = *(const half8*)&qh[(size_t)myq * 128 + kd * 16 + hi * 8];

  floatx16 oacc[4];
#pragma unroll
  for (int di = 0; di < 4; ++di)
#pragma unroll
    for (int j = 0; j < 16; ++j) oacc[di][j] = 0.f;
  float mrun = -1e30f, lrun = 0.f;

  const int krow = tid >> 4, kgrp = tid & 15;  // K: 32 rows x 16 groups per call
  const int vrow = tid >> 3, vgrp = tid & 7;   // V: 64 rows x 8 groups per call

#define STAGE_KV(p, t)                                                                     \
  do {                                                                                     \
    const _Float16* kg_ = kh + (size_t)(t) * 64 * 128;                                     \
    _Pragma("unroll") for (int c = 0; c < 2; ++c) {                                        \
      int row = c * 32 + krow;                                                             \
      gld16(kg_ + row * 128 + ((kgrp ^ SWZ(row)) * 8), &kbuf[p][(c * 32 + w * 4) * 128]);  \
    }                                                                                      \
    _Pragma("unroll") for (int c = 0; c < 2; ++c) {                                        \
      int row = c * 64 + vrow;                                                             \
      gld16(vh + (size_t)row * 2048 + (size_t)(t) * 64 + ((vgrp ^ (row & 7)) * 8),         \
            &vbuf[p][(c * 64 + w * 8) * 64]);                                              \
    }                                                                                      \
  } while (0)

  const int nsteps = 4 * qb + 4;
  STAGE_KV(0, 0);

  for (int s = 0; s < nsteps; ++s) {
    const int cur = s & 1;
    __syncthreads();  // close step s-1's LDS reads before restaging buf^1
    const int sn = (s + 1 < nsteps) ? s + 1 : s;  // clamped redundant restage, never read
    STAGE_KV(cur ^ 1, sn);
    asm volatile("s_waitcnt vmcnt(4)" ::: "memory");  // step-s 4 DMAs landed; s+1's in flight
    __syncthreads();  // all waves have step-s K/V

    floatx16 sacc[2];
#pragma unroll
    for (int ni = 0; ni < 2; ++ni)
#pragma unroll
      for (int j = 0; j < 16; ++j) sacc[ni][j] = 0.f;
    __builtin_amdgcn_s_setprio(1);
#pragma unroll
    for (int ni = 0; ni < 2; ++ni) {
      int rb = (ni * 32 + l32) * 128;
#pragma unroll
      for (int kd = 0; kd < 8; ++kd) {
        half8 ka = *(const half8*)&kbuf[cur][rb + (((kd * 2 + hi) ^ swl) * 8)];
        sacc[ni] = __builtin_amdgcn_mfma_f32_32x32x16_f16(ka, bq[kd], sacc[ni], 0, 0, 0);
      }
    }
    __builtin_amdgcn_s_setprio(0);

    if (s >= 4 * qb) {  // diagonal band: causal mask
      int kv0 = s * 64;
#pragma unroll
      for (int ni = 0; ni < 2; ++ni)
#pragma unroll
        for (int g = 0; g < 4; ++g) {
          int kvb = kv0 + ni * 32 + g * 8 + hi * 4;
#pragma unroll
          for (int t = 0; t < 4; ++t)
            if (kvb + t > myq) sacc[ni][g * 4 + t] = -1e30f;
        }
    }

    float tm = -1e30f;
#pragma unroll
    for (int ni = 0; ni < 2; ++ni)
#pragma unroll
      for (int j = 0; j < 16; ++j) tm = fmaxf(tm, sacc[ni][j]);
    tm = fmaxf(tm, __shfl_xor(tm, 32));
    float nm = fmaxf(mrun, tm);
    float al = exp2f(mrun - nm);
    mrun = nm;
    float ts = 0.f;
#pragma unroll
    for (int ni = 0; ni < 2; ++ni)
#pragma unroll
      for (int j = 0; j < 16; ++j) {
        float p = exp2f(sacc[ni][j] - nm);
        sacc[ni][j] = p;
        ts += p;
      }
    ts += __shfl_xor(ts, 32);
    lrun = lrun * al + ts;
#pragma unroll
    for (int di = 0; di < 4; ++di)
#pragma unroll
      for (int j = 0; j < 16; ++j) oacc[di][j] *= al;

    // P^T write: rows are wave-private (each lane writes/reads only row ql) -> no barrier.
#pragma unroll
    for (int ni = 0; ni < 2; ++ni)
#pragma unroll
      for (int g = 0; g < 4; ++g) {
        half4 p4;
#pragma unroll
        for (int t = 0; t < 4; ++t) p4[t] = (_Float16)sacc[ni][g * 4 + t];
        *(half4*)&pbuf[ql * 64 + (((ni * 4 + g) ^ swq7) * 8) + hi * 4] = p4;
      }

    __builtin_amdgcn_s_setprio(1);
#pragma unroll
    for (int ks = 0; ks < 4; ++ks) {
      half8 pb = *(const half8*)&pbuf[ql * 64 + (((ks * 2 + hi) ^ swq7) * 8)];
#pragma unroll
      for (int di = 0; di < 4; ++di) {
        int rv = (di * 32 + l32) * 64;
        half8 va = *(const half8*)&vbuf[cur][rv + (((ks * 2 + hi) ^ (l32 & 7)) * 8)];
        oacc[di] = __builtin_amdgcn_mfma_f32_32x32x16_f16(va, pb, oacc[di], 0, 0, 0);
      }
    }
    __builtin_amdgcn_s_setprio(0);
  }
  asm volatile("s_waitcnt vmcnt(0)" ::: "memory");  // drain redundant tail stage

  float inv = 1.f / lrun;
  _Float16* ob = att + ((size_t)b * 2048 + myq) * 4096 + h * 128;
#pragma unroll
  for (int di = 0; di < 4; ++di)
#pragma unroll
    for (int g = 0; g < 4; ++g) {
      half4 o4;
#pragma unroll
      for (int t = 0; t < 4; ++t) o4[t] = (_Float16)(oacc[di][g * 4 + t] * inv);
      *(half4*)&ob[di * 32 + g * 8 + hi * 4] = o4;
    }
#undef STAGE_KV
}

extern "C" void kernel_launch(void* const* d_in, const int* in_sizes, int n_in, void* d_out,
                              int out_size, void* d_ws, size_t ws_size, hipStream_t stream) {
  const float* x = (const float*)d_in[0];
  const float* cosb = (const float*)d_in[1];
  const float* sinb = (const float*)d_in[2];
  const float* Wq = (const float*)d_in[3];
  const float* bq = (const float*)d_in[4];
  const float* Wk = (const float*)d_in[5];
  const float* bk = (const float*)d_in[6];
  const float* Wv = (const float*)d_in[7];
  const float* bv = (const float*)d_in[8];
  const float* Wo = (const float*)d_in[9];
  float* out = (float*)d_out;

  char* p = (char*)d_ws;
  _Float16* xb = (_Float16*)p;   p += (size_t)4096 * 4096 * 2;
  _Float16* wqkv = (_Float16*)p; p += (size_t)6144 * 4096 * 2;
  _Float16* wo_b = (_Float16*)p; p += (size_t)4096 * 4096 * 2;
  _Float16* qkv = (_Float16*)p;  p += (size_t)4096 * 6144 * 2;
  _Float16* q_r = (_Float16*)p;  p += (size_t)2 * 32 * 2048 * 128 * 2;
  _Float16* k_r = (_Float16*)p;  p += (size_t)2 * 8 * 2048 * 128 * 2;
  _Float16* v_t = (_Float16*)p;  p += (size_t)2 * 8 * 128 * 2048 * 2;
  _Float16* att = (_Float16*)p;  p += (size_t)4096 * 4096 * 2;
  float* biasc = (float*)p;      p += 6144 * 4;

  convert_all<<<28696, 256, 0, stream>>>(x, Wq, Wk, Wv, Wo, bq, bk, bv, xb, wqkv, wo_b, biasc);

  gemm_bt<_Float16, true><<<dim3(48, 32), 256, 0, stream>>>(xb, wqkv, biasc, qkv, 4096, 6144, 4096);
  rope_qk<<<40960, 256, 0, stream>>>(qkv, cosb, sinb, q_r, k_r);
  v_transpose<<<dim3(64, 4, 16), 256, 0, stream>>>(qkv, v_t);
  attn_kernel<<<dim3(8, 32, 2), 512, 0, stream>>>(q_r, k_r, v_t, att);
  gemm256<float, false><<<dim3(16, 16), 512, 0, stream>>>(att, wo_b, nullptr, out, 4096, 4096, 4096);
}

// Round 4
// 833.429 us; speedup vs baseline: 1.0852x; 1.0852x over previous
//
#include <hip/hip_runtime.h>

typedef _Float16 half8 __attribute__((ext_vector_type(8)));
typedef _Float16 half4 __attribute__((ext_vector_type(4)));
typedef _Float16 half2v __attribute__((ext_vector_type(2)));
typedef float floatx4 __attribute__((ext_vector_type(4)));
typedef float floatx16 __attribute__((ext_vector_type(16)));

// LDS column-group swizzle (8-elem granularity) so fragment reads spread banks.
#define SWZ(r) ((((r) & 7) << 1) | (((r) >> 3) & 1))

__device__ __forceinline__ void gld16(const void* g, void* l) {
  __builtin_amdgcn_global_load_lds(
      (const __attribute__((address_space(1))) unsigned int*)g,
      (__attribute__((address_space(3))) unsigned int*)l, 16, 0, 0);
}

// ---------------- fused fp32 -> f16 converts + bias concat (1 dispatch) ----------------
__global__ void convert_all(const float* __restrict__ x, const float* __restrict__ Wq,
                            const float* __restrict__ Wk, const float* __restrict__ Wv,
                            const float* __restrict__ Wo, const float* __restrict__ bq,
                            const float* __restrict__ bk, const float* __restrict__ bv,
                            _Float16* __restrict__ xb, _Float16* __restrict__ wqkv,
                            _Float16* __restrict__ wo_b, float* __restrict__ biasc) {
  long i = (long)blockIdx.x * 256 + threadIdx.x;
  const long N0 = 2097152, N1 = N0 + 2097152, N2 = N1 + 524288, N3 = N2 + 524288,
             N4 = N3 + 2097152;
  const float* s;
  _Float16* d;
  long j;
  if (i < N0) { s = x; d = xb; j = i; }
  else if (i < N1) { s = Wq; d = wqkv; j = i - N0; }
  else if (i < N2) { s = Wk; d = wqkv + (size_t)4096 * 4096; j = i - N1; }
  else if (i < N3) { s = Wv; d = wqkv + (size_t)5120 * 4096; j = i - N2; }
  else if (i < N4) { s = Wo; d = wo_b; j = i - N3; }
  else {
    long k = i - N4;
    if (k < 4096) biasc[k] = bq[k];
    else if (k < 5120) biasc[k] = bk[k - 4096];
    else if (k < 6144) biasc[k] = bv[k - 5120];
    return;
  }
  float4 a = ((const float4*)s)[2 * j];
  float4 b2 = ((const float4*)s)[2 * j + 1];
  half8 h;
  h[0] = (_Float16)a.x; h[1] = (_Float16)a.y; h[2] = (_Float16)a.z; h[3] = (_Float16)a.w;
  h[4] = (_Float16)b2.x; h[5] = (_Float16)b2.y; h[6] = (_Float16)b2.z; h[7] = (_Float16)b2.w;
  ((half8*)d)[j] = h;
}

// ---------------- QKV GEMM with fused RoPE + V-transpose epilogue ----------------
// C[m,n] = sum_k A[m,k]*B[n,k] + bias[n]. 128x128 tile, BK=64, 4 waves 2x2, 16x16x32.
// Each 128-col tile = exactly one head: hh<32 -> RoPE*scale -> q_r; hh<40 -> RoPE -> k_r;
// else transposed (d-major) store -> v_t. C-tile staged in LDS (stride 130: V-path
// transpose read is then 2-way bank aliased = free).
__global__ __launch_bounds__(256) void gemm_qkv_fused(
    const _Float16* __restrict__ A, const _Float16* __restrict__ B,
    const float* __restrict__ bias, const float* __restrict__ cosb,
    const float* __restrict__ sinb, _Float16* __restrict__ q_r,
    _Float16* __restrict__ k_r, _Float16* __restrict__ v_t, int M, int N, int K) {
  __shared__ _Float16 smem[128 * 130];  // K-loop: as|bs (2x128x64); epilogue: C-tile [128][130]
  _Float16* as = smem;
  _Float16* bs = smem + 128 * 64;
  const int tid = threadIdx.x;
  const int w = tid >> 6, lane = tid & 63;
  const int quad = lane >> 4, l16 = lane & 15;
  const int M0 = blockIdx.y * 128, N0 = blockIdx.x * 128;
  const int wm = (w >> 1) * 64, wn = (w & 1) * 64;

  floatx4 acc[4][4];
#pragma unroll
  for (int i = 0; i < 4; ++i)
#pragma unroll
    for (int j = 0; j < 4; ++j) acc[i][j] = (floatx4){0.f, 0.f, 0.f, 0.f};

  const int sr = tid >> 3, g0 = tid & 7;
  const int csw = (g0 ^ (sr & 7)) * 8;
  const _Float16* Ag[4];
  const _Float16* Bg[4];
  _Float16* asd[4];
  _Float16* bsd[4];
#pragma unroll
  for (int c = 0; c < 4; ++c) {
    Ag[c] = A + (size_t)(M0 + c * 32 + sr) * K + csw;
    Bg[c] = B + (size_t)(N0 + c * 32 + sr) * K + csw;
    asd[c] = &as[(c * 32 + w * 8) * 64];
    bsd[c] = &bs[(c * 32 + w * 8) * 64];
  }

  int aoff[4][2], boff[4][2];
#pragma unroll
  for (int mi = 0; mi < 4; ++mi)
#pragma unroll
    for (int kd = 0; kd < 2; ++kd) {
      int ra = wm + mi * 16 + l16;
      aoff[mi][kd] = ra * 64 + (((kd * 4 + quad) ^ (ra & 7)) * 8);
      int rb = wn + mi * 16 + l16;
      boff[mi][kd] = rb * 64 + (((kd * 4 + quad) ^ (rb & 7)) * 8);
    }

  for (int kk = 0; kk < K; kk += 64) {
    __syncthreads();
#pragma unroll
    for (int c = 0; c < 4; ++c) gld16(Ag[c] + kk, asd[c]);
#pragma unroll
    for (int c = 0; c < 4; ++c) gld16(Bg[c] + kk, bsd[c]);
    __syncthreads();
#pragma unroll
    for (int kd = 0; kd < 2; ++kd) {
      half8 af[4], bf[4];
#pragma unroll
      for (int i = 0; i < 4; ++i) af[i] = *(const half8*)&as[aoff[i][kd]];
#pragma unroll
      for (int i = 0; i < 4; ++i) bf[i] = *(const half8*)&bs[boff[i][kd]];
#pragma unroll
      for (int mi = 0; mi < 4; ++mi)
#pragma unroll
        for (int ni = 0; ni < 4; ++ni)
          acc[mi][ni] = __builtin_amdgcn_mfma_f32_16x16x32_f16(af[mi], bf[ni], acc[mi][ni], 0, 0, 0);
    }
  }

  // ---- epilogue: stage C-tile (bias added) into LDS, then per-head transform ----
  __syncthreads();
#pragma unroll
  for (int mi = 0; mi < 4; ++mi)
#pragma unroll
    for (int ni = 0; ni < 4; ++ni) {
      int col = wn + ni * 16 + l16;
      float bvv = bias[N0 + col];
#pragma unroll
      for (int r = 0; r < 4; ++r) {
        int row = wm + mi * 16 + quad * 4 + r;
        smem[row * 130 + col] = (_Float16)(acc[mi][ni][r] + bvv);
      }
    }
  __syncthreads();

  const int hh = blockIdx.x;   // 0..31 Q head, 32..39 K head, 40..47 V head
  const int bb = M0 >> 11;     // batch
  const int sl0 = M0 & 2047;   // seq offset of this row-block

  if (hh < 40) {
    _Float16* base = (hh < 32)
        ? q_r + ((size_t)(bb * 32 + hh) * 2048 + sl0) * 128
        : k_r + ((size_t)(bb * 8 + (hh - 32)) * 2048 + sl0) * 128;
    const float sc = (hh < 32) ? 0.12751744737079736f : 1.0f;  // log2(e)/sqrt(128) for Q
    const int d4 = (tid & 15) * 4, r0 = tid >> 4;
#pragma unroll
    for (int pp = 0; pp < 8; ++pp) {
      int row = r0 + pp * 16;
      int sl = sl0 + row;
      float4 cc = *(const float4*)&cosb[sl * 128 + d4];
      float4 ss = *(const float4*)&sinb[sl * 128 + d4];
      half4 x1 = *(const half4*)&smem[row * 130 + d4];
      half4 x2 = *(const half4*)&smem[row * 130 + d4 + 64];
      const float* cf = (const float*)&cc;
      const float* sf = (const float*)&ss;
      half4 o1, o2;
#pragma unroll
      for (int i = 0; i < 4; ++i) {
        float xx1 = (float)x1[i], xx2 = (float)x2[i];
        o1[i] = (_Float16)((xx1 * cf[i] - xx2 * sf[i]) * sc);
        o2[i] = (_Float16)((xx2 * cf[i] + xx1 * sf[i]) * sc);
      }
      *(half4*)&base[(size_t)row * 128 + d4] = o1;
      *(half4*)&base[(size_t)row * 128 + d4 + 64] = o2;
    }
  } else {
    const int hv = hh - 40;
    _Float16* vb = v_t + (size_t)(bb * 8 + hv) * 128 * 2048 + sl0;
    const int d0 = tid >> 6, sp = (tid & 63) * 2;
#pragma unroll
    for (int pp = 0; pp < 32; ++pp) {
      int d = d0 + pp * 4;
      half2v o;
      o[0] = smem[sp * 130 + d];
      o[1] = smem[(sp + 1) * 130 + d];
      *(half2v*)&vb[(size_t)d * 2048 + sp] = o;
    }
  }
}

// ---------------- GEMM 256x256 8-phase (out-proj: 256 blocks = 1/CU exactly) --------
template <typename OutT, bool HasBias>
__global__ __launch_bounds__(512, 2) void gemm256(const _Float16* __restrict__ A,
                                                  const _Float16* __restrict__ B,
                                                  const float* __restrict__ bias,
                                                  OutT* __restrict__ C, int M, int N, int K) {
  __shared__ _Float16 as[2][256 * 64];
  __shared__ _Float16 bs[2][256 * 64];
  const int tid = threadIdx.x;
  const int w = tid >> 6, lane = tid & 63;
  const int quad = lane >> 4, l16 = lane & 15;
  const int sw7 = l16 & 7;
  const int M0 = blockIdx.y * 256, N0 = blockIdx.x * 256;
  const int wm = (w >> 2) * 128, wn = (w & 3) * 64;
  const int NT = K >> 6;

  floatx4 acc[8][4];
#pragma unroll
  for (int i = 0; i < 8; ++i)
#pragma unroll
    for (int j = 0; j < 4; ++j) acc[i][j] = (floatx4){0.f, 0.f, 0.f, 0.f};

  const int sr = tid >> 3;
  const int csw = ((tid & 7) ^ (sr & 7)) * 8;
  const _Float16* Ag[4];
  const _Float16* Bg[4];
#pragma unroll
  for (int j = 0; j < 4; ++j) {
    Ag[j] = A + (size_t)(M0 + j * 64 + sr) * K + csw;
    Bg[j] = B + (size_t)(N0 + j * 64 + sr) * K + csw;
  }

#define STA(p, t, j) gld16(Ag[j] + (size_t)(t) * 64, &as[p][(j) * 4096 + w * 512])
#define STB(p, t, j) gld16(Bg[j] + (size_t)(t) * 64, &bs[p][(j) * 4096 + w * 512])

#define FRA(p, q, mi, kd) \
  (*(const half8*)&as[p][(wm + (q) * 32 + (mi) * 16 + l16) * 64 + ((((kd) * 4 + quad) ^ sw7) * 8)])
#define FRB(p, ni, kd) \
  (*(const half8*)&bs[p][(wn + (ni) * 16 + l16) * 64 + ((((kd) * 4 + quad) ^ sw7) * 8)])

#define LD_A(p, q)                                   \
  _Pragma("unroll") for (int kd = 0; kd < 2; ++kd)   \
  _Pragma("unroll") for (int mi = 0; mi < 2; ++mi)   \
      af[mi][kd] = FRA(p, q, mi, kd);

#define LD_B(p)                                      \
  _Pragma("unroll") for (int kd = 0; kd < 2; ++kd)   \
  _Pragma("unroll") for (int ni = 0; ni < 4; ++ni)   \
      bf[ni][kd] = FRB(p, ni, kd);

#define PH_COMPUTE(q)                                                                  \
  __builtin_amdgcn_s_barrier();                                                        \
  asm volatile("s_waitcnt lgkmcnt(0)" ::: "memory");                                   \
  __builtin_amdgcn_sched_barrier(0);                                                   \
  __builtin_amdgcn_s_setprio(1);                                                       \
  _Pragma("unroll") for (int kd = 0; kd < 2; ++kd)                                     \
  _Pragma("unroll") for (int mi = 0; mi < 2; ++mi)                                     \
  _Pragma("unroll") for (int ni = 0; ni < 4; ++ni)                                     \
      acc[(q) * 2 + mi][ni] = __builtin_amdgcn_mfma_f32_16x16x32_f16(                  \
          af[mi][kd], bf[ni][kd], acc[(q) * 2 + mi][ni], 0, 0, 0);                     \
  __builtin_amdgcn_s_setprio(0);

  half8 bf[4][2], af[2][2];

  STA(0, 0, 0); STA(0, 0, 1); STA(0, 0, 2); STA(0, 0, 3);
  STB(0, 0, 0); STB(0, 0, 1); STB(0, 0, 2); STB(0, 0, 3);
  STB(1, 1, 0); STB(1, 1, 1); STB(1, 1, 2); STB(1, 1, 3);
  asm volatile("s_waitcnt vmcnt(4)" ::: "memory");
  __builtin_amdgcn_s_barrier();

  for (int t = 0; t < NT; t += 2) {
    const int t2 = (t + 2 < NT) ? t + 2 : t;
    const int t3 = (t + 3 < NT) ? t + 3 : t + 1;

    LD_B(0); LD_A(0, 0);
    STA(1, t + 1, 0); STA(1, t + 1, 1); STA(1, t + 1, 2); STA(1, t + 1, 3);
    PH_COMPUTE(0);
    __builtin_amdgcn_s_barrier();

    LD_A(0, 1);
    STB(0, t2, 0); STB(0, t2, 1);
    PH_COMPUTE(1);
    __builtin_amdgcn_s_barrier();

    LD_A(0, 2);
    STB(0, t2, 2); STB(0, t2, 3);
    PH_COMPUTE(2);
    __builtin_amdgcn_s_barrier();

    LD_A(0, 3);
    PH_COMPUTE(3);
    asm volatile("s_waitcnt vmcnt(4)" ::: "memory");
    __builtin_amdgcn_sched_barrier(0);
    __builtin_amdgcn_s_barrier();

    LD_B(1); LD_A(1, 0);
    STA(0, t2, 0); STA(0, t2, 1);
    PH_COMPUTE(0);
    __builtin_amdgcn_s_barrier();

    LD_A(1, 1);
    STA(0, t2, 2); STA(0, t2, 3);
    PH_COMPUTE(1);
    __builtin_amdgcn_s_barrier();

    LD_A(1, 2);
    STB(1, t3, 0); STB(1, t3, 1);
    PH_COMPUTE(2);
    __builtin_amdgcn_s_barrier();

    LD_A(1, 3);
    STB(1, t3, 2); STB(1, t3, 3);
    PH_COMPUTE(3);
    asm volatile("s_waitcnt vmcnt(4)" ::: "memory");
    __builtin_amdgcn_sched_barrier(0);
    __builtin_amdgcn_s_barrier();
  }
  asm volatile("s_waitcnt vmcnt(0)" ::: "memory");

#pragma unroll
  for (int mf = 0; mf < 8; ++mf)
#pragma unroll
    for (int ni = 0; ni < 4; ++ni) {
      int row = M0 + wm + mf * 16 + quad * 4;
      int col = N0 + wn + ni * 16 + l16;
      float bvv = HasBias ? bias[col] : 0.f;
#pragma unroll
      for (int r = 0; r < 4; ++r) C[(size_t)(row + r) * N + col] = (OutT)(acc[mf][ni][r] + bvv);
    }
#undef STA
#undef STB
#undef FRA
#undef FRB
#undef LD_A
#undef LD_B
#undef PH_COMPUTE
}

// ---------------- Flash attention: S^T form, 32x32x16 MFMA (R2-proven version) ----------------
// KVBLK=64, K/V double-buffered (LDS 64KB -> 2 blocks/CU), stage of step s+1
// issued before compute of step s, counted vmcnt(8) (never 0 in main loop).
__global__ __launch_bounds__(256, 2) void attn_kernel(const _Float16* __restrict__ q_r,
                                                      const _Float16* __restrict__ k_r,
                                                      const _Float16* __restrict__ v_t,
                                                      _Float16* __restrict__ att) {
  __shared__ __align__(16) _Float16 kbuf[2][64 * 128];  // K [kv64][d128]; later P^T [q128][kv64]
  __shared__ __align__(16) _Float16 vbuf[2][128 * 64];  // V^T [d128][kv64]
  const int tid = threadIdx.x;
  const int w = tid >> 6, lane = tid & 63;
  const int l32 = lane & 31, hi = lane >> 5;
  const int qb = 15 - blockIdx.x;  // heavy q-tiles dispatch first
  const int h = blockIdx.y, b = blockIdx.z;
  const int q0 = qb * 128;
  const _Float16* qh = q_r + ((size_t)(b * 32 + h) * 2048) * 128;
  const _Float16* kh = k_r + ((size_t)(b * 8 + (h >> 2)) * 2048) * 128;
  const _Float16* vh = v_t + ((size_t)(b * 8 + (h >> 2)) * 128) * 2048;

  const int ql = w * 32 + l32;
  const int myq = q0 + ql;
  const int swq7 = ql & 7;   // 8-group swizzle key for 64-wide P rows
  const int swl = SWZ(l32);  // 16-group swizzle key for 128-wide K rows

  half8 bq[8];
#pragma unroll
  for (int kd = 0; kd < 8; ++kd)
    bq[kd] = *(const half8*)&qh[(size_t)myq * 128 + kd * 16 + hi * 8];

  floatx16 oacc[4];
#pragma unroll
  for (int di = 0; di < 4; ++di)
#pragma unroll
    for (int j = 0; j < 16; ++j) oacc[di][j] = 0.f;
  float mrun = -1e30f, lrun = 0.f;

  const int krow = tid >> 4, kgrp = tid & 15;  // K staging: 16 rows x 16 groups per call
  const int vrow = tid >> 3, vgrp = tid & 7;   // V staging: 32 rows x 8 groups per call

#define STAGE_KV(p, t)                                                                     \
  do {                                                                                     \
    const _Float16* kg_ = kh + (size_t)(t) * 64 * 128;                                     \
    _Pragma("unroll") for (int c = 0; c < 4; ++c) {                                        \
      int row = c * 16 + krow;                                                             \
      gld16(kg_ + row * 128 + ((kgrp ^ SWZ(row)) * 8), &kbuf[p][(c * 16 + w * 4) * 128]);  \
    }                                                                                      \
    _Pragma("unroll") for (int c = 0; c < 4; ++c) {                                        \
      int row = c * 32 + vrow;                                                             \
      gld16(vh + (size_t)row * 2048 + (size_t)(t) * 64 + ((vgrp ^ (row & 7)) * 8),         \
            &vbuf[p][(c * 32 + w * 8) * 64]);                                              \
    }                                                                                      \
  } while (0)

  const int nsteps = 2 * qb + 2;
  STAGE_KV(0, 0);

  for (int s = 0; s < nsteps; ++s) {
    const int cur = s & 1;
    __syncthreads();  // close step s-1's LDS reads before restaging buf^1
    const int sn = (s + 1 < nsteps) ? s + 1 : s;  // clamped redundant restage, never read
    STAGE_KV(cur ^ 1, sn);
    asm volatile("s_waitcnt vmcnt(8)" ::: "memory");  // step-s 8 DMAs landed; s+1's in flight
    __syncthreads();  // all waves have step-s K/V

    floatx16 sacc[2];
#pragma unroll
    for (int ni = 0; ni < 2; ++ni)
#pragma unroll
      for (int j = 0; j < 16; ++j) sacc[ni][j] = 0.f;
#pragma unroll
    for (int ni = 0; ni < 2; ++ni) {
      int rb = (ni * 32 + l32) * 128;
#pragma unroll
      for (int kd = 0; kd < 8; ++kd) {
        half8 ka = *(const half8*)&kbuf[cur][rb + (((kd * 2 + hi) ^ swl) * 8)];
        sacc[ni] = __builtin_amdgcn_mfma_f32_32x32x16_f16(ka, bq[kd], sacc[ni], 0, 0, 0);
      }
    }

    if (s >= 2 * qb) {  // diagonal: causal mask
      int kv0 = s * 64;
#pragma unroll
      for (int ni = 0; ni < 2; ++ni)
#pragma unroll
        for (int g = 0; g < 4; ++g) {
          int kvb = kv0 + ni * 32 + g * 8 + hi * 4;
#pragma unroll
          for (int t = 0; t < 4; ++t)
            if (kvb + t > myq) sacc[ni][g * 4 + t] = -1e30f;
        }
    }

    float tm = -1e30f;
#pragma unroll
    for (int ni = 0; ni < 2; ++ni)
#pragma unroll
      for (int j = 0; j < 16; ++j) tm = fmaxf(tm, sacc[ni][j]);
    tm = fmaxf(tm, __shfl_xor(tm, 32));
    float nm = fmaxf(mrun, tm);
    float al = exp2f(mrun - nm);
    mrun = nm;
    float ts = 0.f;
#pragma unroll
    for (int ni = 0; ni < 2; ++ni)
#pragma unroll
      for (int j = 0; j < 16; ++j) {
        float p = exp2f(sacc[ni][j] - nm);
        sacc[ni][j] = p;
        ts += p;
      }
    ts += __shfl_xor(ts, 32);
    lrun = lrun * al + ts;
#pragma unroll
    for (int di = 0; di < 4; ++di)
#pragma unroll
      for (int j = 0; j < 16; ++j) oacc[di][j] *= al;

    __syncthreads();  // all waves' K reads done before P^T overwrite

#pragma unroll
    for (int ni = 0; ni < 2; ++ni)
#pragma unroll
      for (int g = 0; g < 4; ++g) {
        half4 p4;
#pragma unroll
        for (int t = 0; t < 4; ++t) p4[t] = (_Float16)sacc[ni][g * 4 + t];
        *(half4*)&kbuf[cur][ql * 64 + (((ni * 4 + g) ^ swq7) * 8) + hi * 4] = p4;
      }

    // P rows are wave-private: no barrier needed before PV reads of own rows.
#pragma unroll
    for (int ks = 0; ks < 4; ++ks) {
      half8 pb = *(const half8*)&kbuf[cur][ql * 64 + (((ks * 2 + hi) ^ swq7) * 8)];
#pragma unroll
      for (int di = 0; di < 4; ++di) {
        int rv = (di * 32 + l32) * 64;
        half8 va = *(const half8*)&vbuf[cur][rv + (((ks * 2 + hi) ^ (l32 & 7)) * 8)];
        oacc[di] = __builtin_amdgcn_mfma_f32_32x32x16_f16(va, pb, oacc[di], 0, 0, 0);
      }
    }
  }
  asm volatile("s_waitcnt vmcnt(0)" ::: "memory");  // drain redundant tail stage

  float inv = 1.f / lrun;
  _Float16* ob = att + ((size_t)b * 2048 + myq) * 4096 + h * 128;
#pragma unroll
  for (int di = 0; di < 4; ++di)
#pragma unroll
    for (int g = 0; g < 4; ++g) {
      half4 o4;
#pragma unroll
      for (int t = 0; t < 4; ++t) o4[t] = (_Float16)(oacc[di][g * 4 + t] * inv);
      *(half4*)&ob[di * 32 + g * 8 + hi * 4] = o4;
    }
#undef STAGE_KV
}

extern "C" void kernel_launch(void* const* d_in, const int* in_sizes, int n_in, void* d_out,
                              int out_size, void* d_ws, size_t ws_size, hipStream_t stream) {
  const float* x = (const float*)d_in[0];
  const float* cosb = (const float*)d_in[1];
  const float* sinb = (const float*)d_in[2];
  const float* Wq = (const float*)d_in[3];
  const float* bq = (const float*)d_in[4];
  const float* Wk = (const float*)d_in[5];
  const float* bk = (const float*)d_in[6];
  const float* Wv = (const float*)d_in[7];
  const float* bv = (const float*)d_in[8];
  const float* Wo = (const float*)d_in[9];
  float* out = (float*)d_out;

  char* p = (char*)d_ws;
  _Float16* xb = (_Float16*)p;   p += (size_t)4096 * 4096 * 2;
  _Float16* wqkv = (_Float16*)p; p += (size_t)6144 * 4096 * 2;
  _Float16* wo_b = (_Float16*)p; p += (size_t)4096 * 4096 * 2;
  _Float16* q_r = (_Float16*)p;  p += (size_t)2 * 32 * 2048 * 128 * 2;
  _Float16* k_r = (_Float16*)p;  p += (size_t)2 * 8 * 2048 * 128 * 2;
  _Float16* v_t = (_Float16*)p;  p += (size_t)2 * 8 * 128 * 2048 * 2;
  _Float16* att = (_Float16*)p;  p += (size_t)4096 * 4096 * 2;
  float* biasc = (float*)p;      p += 6144 * 4;

  convert_all<<<28696, 256, 0, stream>>>(x, Wq, Wk, Wv, Wo, bq, bk, bv, xb, wqkv, wo_b, biasc);

  gemm_qkv_fused<<<dim3(48, 32), 256, 0, stream>>>(xb, wqkv, biasc, cosb, sinb, q_r, k_r, v_t,
                                                   4096, 6144, 4096);
  attn_kernel<<<dim3(16, 32, 2), 256, 0, stream>>>(q_r, k_r, v_t, att);
  gemm256<float, false><<<dim3(16, 16), 512, 0, stream>>>(att, wo_b, nullptr, out, 4096, 4096, 4096);
}